// Round 1
// baseline (348.160 us; speedup 1.0000x reference)
//
#include <hip/hip_runtime.h>
#include <cstdint>
#include <cstddef>

// CRF NLL forward. B=256 sequences, T=512 steps, L=64 labels.
// One wave (64 lanes) per batch element; lane index = label j.
// Scaled linear-domain forward algorithm:
//   alpha'_j = (sum_i alpha_i * E_ij) * exp(emit_t_j),  E = exp(trans)
// with shuffle-max renormalization every 4 steps (log-scale accumulated in c).
// E column lives in 64 VGPRs per lane; alpha_i broadcast via v_readlane.

constexpr int Bc = 256;
constexpr int Tc = 512;
constexpr int Lc = 64;

__device__ __forceinline__ float lane_bcast(float v, int lane) {
    return __uint_as_float(__builtin_amdgcn_readlane(__float_as_uint(v), lane));
}

__global__ __launch_bounds__(64, 1) void crf_nll_kernel(
    const float* __restrict__ y_true,
    const float* __restrict__ y_pred,
    const float* __restrict__ trans,
    float* __restrict__ out)
{
    const int b = blockIdx.x;
    const int j = threadIdx.x;  // 0..63 == label index

    // E[i][j] = exp(trans[i][j]); lane j holds column j in 64 VGPRs.
    float Ecol[Lc];
    #pragma unroll
    for (int i = 0; i < Lc; ++i)
        Ecol[i] = __expf(trans[i * Lc + j]);

    const float* yp = y_pred + (size_t)b * Tc * Lc;
    const float* yt = y_true + (size_t)b * Tc * Lc;

    // t = 0 plus depth-2 prefetch of the streaming loads.
    float yp0  = yp[j],          yt0  = yt[j];
    float ypn1 = yp[Lc + j],     ytn1 = yt[Lc + j];
    float ypn2 = yp[2 * Lc + j], ytn2 = yt[2 * Lc + j];

    float psum = yp0 * yt0;   // point score, per-lane partial
    float tsum = 0.0f;        // transition score, per-lane partial

    unsigned long long mask0 = __ballot(yt0 > 0.5f);
    int l_prev = (int)__builtin_ctzll(mask0);

    // init: alpha_j = exp(y_pred[b,0,j] - max_j), c = max_j
    float mx = yp0;
    #pragma unroll
    for (int k = 1; k < 64; k <<= 1) mx = fmaxf(mx, __shfl_xor(mx, k));
    float alpha = __expf(yp0 - mx);
    float c = mx;

    for (int t = 1; t < Tc; ++t) {
        const float ypc = ypn1, ytc = ytn1;
        ypn1 = ypn2; ytn1 = ytn2;
        const int tpre = t + 2;
        if (tpre < Tc) {                     // uniform branch
            ypn2 = yp[tpre * Lc + j];
            ytn2 = yt[tpre * Lc + j];
        }

        const float F    = __expf(ypc);           // exp(emit_t[j])
        const float trow = trans[l_prev * Lc + j]; // L1-hot 256B row

        // matvec: acc_j = sum_i alpha_i * E[i][j]
        float a0 = 0.f, a1 = 0.f, a2 = 0.f, a3 = 0.f;
        #pragma unroll
        for (int i = 0; i < Lc; i += 4) {
            a0 = fmaf(lane_bcast(alpha, i + 0), Ecol[i + 0], a0);
            a1 = fmaf(lane_bcast(alpha, i + 1), Ecol[i + 1], a1);
            a2 = fmaf(lane_bcast(alpha, i + 2), Ecol[i + 2], a2);
            a3 = fmaf(lane_bcast(alpha, i + 3), Ecol[i + 3], a3);
        }
        alpha = ((a0 + a1) + (a2 + a3)) * F;

        psum = fmaf(ypc, ytc, psum);
        tsum = fmaf(ytc, trow, tsum);
        unsigned long long m = __ballot(ytc > 0.5f);
        l_prev = (int)__builtin_ctzll(m);

        // renormalize every 4 steps: worst-case growth ~6e16 between renorms
        if ((t & 3) == 0) {
            float amx = alpha;
            #pragma unroll
            for (int k = 1; k < 64; k <<= 1) amx = fmaxf(amx, __shfl_xor(amx, k));
            c += __logf(amx);
            alpha *= (1.0f / amx);
        }
    }

    // final reductions across the wave
    float asum = alpha;
    #pragma unroll
    for (int k = 1; k < 64; k <<= 1) asum += __shfl_xor(asum, k);
    #pragma unroll
    for (int k = 1; k < 64; k <<= 1) psum += __shfl_xor(psum, k);
    #pragma unroll
    for (int k = 1; k < 64; k <<= 1) tsum += __shfl_xor(tsum, k);

    if (j == 0) {
        const float log_norm = c + __logf(asum);
        out[b] = -(psum + tsum - log_norm);
    }
}

extern "C" void kernel_launch(void* const* d_in, const int* in_sizes, int n_in,
                              void* d_out, int out_size, void* d_ws, size_t ws_size,
                              hipStream_t stream) {
    const float* y_true = (const float*)d_in[0];
    const float* y_pred = (const float*)d_in[1];
    const float* trans  = (const float*)d_in[2];
    float* outp         = (float*)d_out;
    crf_nll_kernel<<<dim3(Bc), dim3(Lc), 0, stream>>>(y_true, y_pred, trans, outp);
}

// Round 2
// 311.669 us; speedup vs baseline: 1.1171x; 1.1171x over previous
//
#include <hip/hip_runtime.h>
#include <cstdint>
#include <cstddef>

// CRF NLL forward. B=256, T=512, L=64. One wave per batch; lane j = label.
// Scaled linear-domain scan: alpha'_j = (sum_i alpha_i * E_ij) * exp(emit_j),
// E = exp(trans) held in 64 VGPRs/lane; alpha_i broadcast via v_readlane.
// R2 changes vs R1:
//  - trans row for the transition score now read from LDS (lgkmcnt), so the
//    per-step wait no longer drains the global-stream prefetch (vmcnt(0) bug).
//  - prefetch deepened to 4 rows, loop unrolled x4 so the rotation is
//    register renaming, not moves.

constexpr int Bc = 256;
constexpr int Tc = 512;
constexpr int Lc = 64;

__device__ __forceinline__ float lane_bcast(float v, int lane) {
    return __uint_as_float(__builtin_amdgcn_readlane(__float_as_uint(v), lane));
}

__global__ __launch_bounds__(64, 1) void crf_nll_kernel(
    const float* __restrict__ y_true,
    const float* __restrict__ y_pred,
    const float* __restrict__ trans,
    float* __restrict__ out)
{
    const int b = blockIdx.x;
    const int j = threadIdx.x;  // label index

    __shared__ float strans[Lc * Lc];  // 16 KB: trans rows for the score term

    // E[i][j] = exp(trans[i][j]); lane j holds column j. Also stage raw trans
    // into LDS (one pass over the same data).
    float Ecol[Lc];
    #pragma unroll
    for (int i = 0; i < Lc; ++i) {
        const float tv = trans[i * Lc + j];
        Ecol[i] = __expf(tv);
        strans[i * Lc + j] = tv;
    }
    __syncthreads();

    const float* yp = y_pred + (size_t)b * Tc * Lc;
    const float* yt = y_true + (size_t)b * Tc * Lc;

    // t = 0
    const float yp0 = yp[j], yt0 = yt[j];
    float psum = yp0 * yt0;
    float tsum = 0.0f;
    int l_prev = (int)__builtin_ctzll(__ballot(yt0 > 0.5f));

    float mx = yp0;
    #pragma unroll
    for (int k = 1; k < 64; k <<= 1) mx = fmaxf(mx, __shfl_xor(mx, k));
    float alpha = __expf(yp0 - mx);
    float c = mx;

    // depth-4 rotating prefetch of rows t=1..4
    float p_yp[4], p_yt[4];
    #pragma unroll
    for (int k = 0; k < 4; ++k) {
        p_yp[k] = yp[(1 + k) * Lc + j];
        p_yt[k] = yt[(1 + k) * Lc + j];
    }

    #pragma unroll 4
    for (int t = 1; t < Tc; ++t) {
        const int slot = (t - 1) & 3;
        const float ypc = p_yp[slot], ytc = p_yt[slot];
        const int tpre = t + 4;
        if (tpre < Tc) {                       // uniform branch
            p_yp[slot] = yp[tpre * Lc + j];
            p_yt[slot] = yt[tpre * Lc + j];
        }

        const float F    = __expf(ypc);
        const float trow = strans[l_prev * Lc + j];  // LDS, 2-way alias = free

        float a0 = 0.f, a1 = 0.f, a2 = 0.f, a3 = 0.f;
        #pragma unroll
        for (int i = 0; i < Lc; i += 4) {
            a0 = fmaf(lane_bcast(alpha, i + 0), Ecol[i + 0], a0);
            a1 = fmaf(lane_bcast(alpha, i + 1), Ecol[i + 1], a1);
            a2 = fmaf(lane_bcast(alpha, i + 2), Ecol[i + 2], a2);
            a3 = fmaf(lane_bcast(alpha, i + 3), Ecol[i + 3], a3);
        }
        alpha = ((a0 + a1) + (a2 + a3)) * F;

        psum = fmaf(ypc, ytc, psum);
        tsum = fmaf(ytc, trow, tsum);
        l_prev = (int)__builtin_ctzll(__ballot(ytc > 0.5f));

        // renorm every 4 steps; growth between renorms <= ~6e16, safe in fp32
        if ((t & 3) == 0) {
            float amx = alpha;
            #pragma unroll
            for (int k = 1; k < 64; k <<= 1) amx = fmaxf(amx, __shfl_xor(amx, k));
            c += __logf(amx);
            alpha *= (1.0f / amx);
        }
    }

    float asum = alpha;
    #pragma unroll
    for (int k = 1; k < 64; k <<= 1) asum += __shfl_xor(asum, k);
    #pragma unroll
    for (int k = 1; k < 64; k <<= 1) psum += __shfl_xor(psum, k);
    #pragma unroll
    for (int k = 1; k < 64; k <<= 1) tsum += __shfl_xor(tsum, k);

    if (j == 0) {
        const float log_norm = c + __logf(asum);
        out[b] = -(psum + tsum - log_norm);
    }
}

extern "C" void kernel_launch(void* const* d_in, const int* in_sizes, int n_in,
                              void* d_out, int out_size, void* d_ws, size_t ws_size,
                              hipStream_t stream) {
    const float* y_true = (const float*)d_in[0];
    const float* y_pred = (const float*)d_in[1];
    const float* trans  = (const float*)d_in[2];
    float* outp         = (float*)d_out;
    crf_nll_kernel<<<dim3(Bc), dim3(Lc), 0, stream>>>(y_true, y_pred, trans, outp);
}

// Round 3
// 204.533 us; speedup vs baseline: 1.7022x; 1.5238x over previous
//
#include <hip/hip_runtime.h>
#include <cstdint>
#include <cstddef>

// CRF NLL forward. B=256, T=512, L=64. One wave per batch; lane j = label.
// Scaled linear-domain scan: alpha'_j = (sum_i alpha_i * E_ij) * exp(emit_j),
// E = exp(trans) in 64 VGPRs/lane; alpha_i broadcast via v_readlane.
// R3 changes vs R2 (all serial-latency removal; 1 wave/SIMD hides nothing):
//  - renorm by lane-0 alpha (1 readlane) instead of 6-stage shfl max
//    (~750 cyc of dependent ds_bpermute latency every 4th step).
//  - trans-row ds_read software-pipelined: issued at step t (after ballot),
//    consumed at step t+1 under the matvec.
//  - stream prefetch: unconditional 8-load block at top of x4-unrolled body,
//    peeled tail; load-to-use distance = one full body (~1200 cyc).

constexpr int Bc = 256;
constexpr int Tc = 512;
constexpr int Lc = 64;

__device__ __forceinline__ float lane_bcast(float v, int lane) {
    return __uint_as_float(__builtin_amdgcn_readlane(__float_as_uint(v), lane));
}

__global__ __launch_bounds__(64, 1) void crf_nll_kernel(
    const float* __restrict__ y_true,
    const float* __restrict__ y_pred,
    const float* __restrict__ trans,
    float* __restrict__ out)
{
    const int b = blockIdx.x;
    const int j = threadIdx.x;  // label index

    __shared__ float strans[Lc * Lc];

    float Ecol[Lc];
    #pragma unroll
    for (int i = 0; i < Lc; ++i) {
        const float tv = trans[i * Lc + j];
        Ecol[i] = __expf(tv);
        strans[i * Lc + j] = tv;
    }
    __syncthreads();

    const float* yp = y_pred + (size_t)b * Tc * Lc + j;
    const float* yt = y_true + (size_t)b * Tc * Lc + j;

    // row 0
    const float yp0 = yp[0], yt0 = yt[0];
    float psum = yp0 * yt0;
    float tsum = 0.0f;
    float c = lane_bcast(yp0, 0);        // reference instead of max: spread <= e^11, safe
    float alpha = __expf(yp0 - c);

    int l0 = (int)__builtin_ctzll(__ballot(yt0 > 0.5f));
    float trow = strans[l0 * Lc + j];    // pipelined: consumed at step t=1

    // one forward step (no renorm). trow holds strans[l_{t-1}] on entry;
    // on exit it holds strans[l_t] (ds_read completes under next matvec).
    auto step = [&](float ypc, float ytc) {
        psum = fmaf(ypc, ytc, psum);
        tsum = fmaf(ytc, trow, tsum);                       // uses last step's read
        const int l_cur = (int)__builtin_ctzll(__ballot(ytc > 0.5f));
        trow = strans[l_cur * Lc + j];                      // for NEXT step
        const float F = __expf(ypc);
        float s0 = 0.f, s1 = 0.f, s2 = 0.f, s3 = 0.f;
        #pragma unroll
        for (int i = 0; i < Lc; i += 4) {
            s0 = fmaf(lane_bcast(alpha, i + 0), Ecol[i + 0], s0);
            s1 = fmaf(lane_bcast(alpha, i + 1), Ecol[i + 1], s1);
            s2 = fmaf(lane_bcast(alpha, i + 2), Ecol[i + 2], s2);
            s3 = fmaf(lane_bcast(alpha, i + 3), Ecol[i + 3], s3);
        }
        alpha = ((s0 + s1) + (s2 + s3)) * F;
    };

    // renorm via lane-0 value: no cross-lane latency chain.
    auto renorm = [&]() {
        const float s = lane_bcast(alpha, 0);
        alpha *= (1.0f / s);
        c += __logf(s);
    };

    // prefetch rows 1..4
    float a_yp = yp[1 * Lc], a_yt = yt[1 * Lc];
    float b_yp = yp[2 * Lc], b_yt = yt[2 * Lc];
    float c_yp = yp[3 * Lc], c_yt = yt[3 * Lc];
    float d_yp = yp[4 * Lc], d_yt = yt[4 * Lc];

    int t = 1;
    #pragma unroll 1
    for (; t + 7 < Tc; t += 4) {
        // unconditional block prefetch of rows t+4..t+7
        const float na_yp = yp[(t + 4) * Lc], na_yt = yt[(t + 4) * Lc];
        const float nb_yp = yp[(t + 5) * Lc], nb_yt = yt[(t + 5) * Lc];
        const float nc_yp = yp[(t + 6) * Lc], nc_yt = yt[(t + 6) * Lc];
        const float nd_yp = yp[(t + 7) * Lc], nd_yt = yt[(t + 7) * Lc];

        step(a_yp, a_yt);
        step(b_yp, b_yt);
        step(c_yp, c_yt);
        step(d_yp, d_yt);
        renorm();   // every 4 steps: growth < e^40 + spread e^11, fp32-safe

        a_yp = na_yp; a_yt = na_yt;
        b_yp = nb_yp; b_yt = nb_yt;
        c_yp = nc_yp; c_yt = nc_yt;
        d_yp = nd_yp; d_yt = nd_yt;
    }

    // tail: rows t..511 (t == 505); a..d hold rows 505..508
    const float e_yp = yp[(t + 4) * Lc], e_yt = yt[(t + 4) * Lc];
    const float f_yp = yp[(t + 5) * Lc], f_yt = yt[(t + 5) * Lc];
    const float g_yp = yp[(t + 6) * Lc], g_yt = yt[(t + 6) * Lc];

    step(a_yp, a_yt);
    step(b_yp, b_yt);
    step(c_yp, c_yt);
    step(d_yp, d_yt);
    renorm();
    step(e_yp, e_yt);
    step(f_yp, f_yt);
    step(g_yp, g_yt);

    // final cross-lane reductions (once; shfl latency irrelevant here)
    float asum = alpha;
    #pragma unroll
    for (int k = 1; k < 64; k <<= 1) asum += __shfl_xor(asum, k);
    #pragma unroll
    for (int k = 1; k < 64; k <<= 1) psum += __shfl_xor(psum, k);
    #pragma unroll
    for (int k = 1; k < 64; k <<= 1) tsum += __shfl_xor(tsum, k);

    if (j == 0) {
        const float log_norm = c + __logf(asum);
        out[b] = -(psum + tsum - log_norm);
    }
}

extern "C" void kernel_launch(void* const* d_in, const int* in_sizes, int n_in,
                              void* d_out, int out_size, void* d_ws, size_t ws_size,
                              hipStream_t stream) {
    const float* y_true = (const float*)d_in[0];
    const float* y_pred = (const float*)d_in[1];
    const float* trans  = (const float*)d_in[2];
    float* outp         = (float*)d_out;
    crf_nll_kernel<<<dim3(Bc), dim3(Lc), 0, stream>>>(y_true, y_pred, trans, outp);
}